// Round 1
// baseline (810.831 us; speedup 1.0000x reference)
//
#include <hip/hip_runtime.h>

#define BATCH 512
#define TT    1024
#define NST   64
#define NSYM  32

// ---------------------------------------------------------------------------
// Prep: softmax(transition) -> ws[0..4095]   (A[i][j], row-major)
//       softmax(emission)   -> ws[4096..6143] (B[n][s], row-major)
//       softmax(init)       -> ws[6144..6207] (I[n])
// ---------------------------------------------------------------------------
__global__ __launch_bounds__(64) void hmm_prep(
    const float* __restrict__ em, const float* __restrict__ tr,
    const float* __restrict__ ini, float* __restrict__ ws)
{
    const int n = threadIdx.x;  // 0..63, one row per lane

    // A row n softmax (64 wide)
    {
        float a[64];
        float m = -1e30f;
        #pragma unroll
        for (int j = 0; j < 64; ++j) { a[j] = tr[n * 64 + j]; m = fmaxf(m, a[j]); }
        float s = 0.f;
        #pragma unroll
        for (int j = 0; j < 64; ++j) { a[j] = __expf(a[j] - m); s += a[j]; }
        const float inv = 1.f / s;
        #pragma unroll
        for (int j = 0; j < 64; ++j) ws[n * 64 + j] = a[j] * inv;
    }
    // B row n softmax (32 wide)
    {
        float b[32];
        float m = -1e30f;
        #pragma unroll
        for (int j = 0; j < 32; ++j) { b[j] = em[n * 32 + j]; m = fmaxf(m, b[j]); }
        float s = 0.f;
        #pragma unroll
        for (int j = 0; j < 32; ++j) { b[j] = __expf(b[j] - m); s += b[j]; }
        const float inv = 1.f / s;
        #pragma unroll
        for (int j = 0; j < 32; ++j) ws[4096 + n * 32 + j] = b[j] * inv;
    }
    // I softmax (cross-lane, 64 wide)
    {
        float v = ini[n];
        float m = v;
        #pragma unroll
        for (int off = 32; off; off >>= 1) m = fmaxf(m, __shfl_xor(m, off, 64));
        const float e = __expf(v - m);
        float s = e;
        #pragma unroll
        for (int off = 32; off; off >>= 1) s += __shfl_xor(s, off, 64);
        ws[6144 + n] = e / s;
    }
}

// ---------------------------------------------------------------------------
// Scan: one wave per batch element, lane = state.
//   lane n holds A-column n (A[i][n], i=0..63) and B-row n in registers.
//   fwd broadcast via double-buffered LDS, read back as float4 (ds_read_b128).
//   x row (wave-uniform address) -> scalar loads -> SGPR-operand FMAs.
// ---------------------------------------------------------------------------
__global__ __launch_bounds__(64) void hmm_scan(
    const float* __restrict__ inputs, const float* __restrict__ ws,
    float* __restrict__ out)
{
    const int b    = blockIdx.x;
    const int lane = threadIdx.x;  // 0..63 = state

    const float* __restrict__ A  = ws;          // [64][64]
    const float* __restrict__ Bm = ws + 4096;   // [64][32]
    const float* __restrict__ Iv = ws + 6144;   // [64]

    // A column `lane` into registers: Acol[i] = A[i][lane]  (coalesced per i)
    float Acol[64];
    #pragma unroll
    for (int i = 0; i < 64; ++i) Acol[i] = A[i * 64 + lane];

    // B row `lane` into registers (float4 loads)
    float Brow[32];
    {
        const float4* B4 = reinterpret_cast<const float4*>(Bm + lane * 32);
        #pragma unroll
        for (int i = 0; i < 8; ++i) {
            float4 v = B4[i];
            Brow[4*i+0] = v.x; Brow[4*i+1] = v.y;
            Brow[4*i+2] = v.z; Brow[4*i+3] = v.w;
        }
    }

    __shared__ float fsh[2][64];

    const float* __restrict__ xp = inputs + (size_t)b * TT * NSYM;
    float* __restrict__ op       = out    + (size_t)b * TT * 65;

    float R  = Iv[lane];   // t=0: R = I (fwd starts at 0, is_init=1)
    float ll = 0.f;

    // x for t=0
    float x[32];
    {
        const float4* x4 = reinterpret_cast<const float4*>(xp);
        #pragma unroll
        for (int i = 0; i < 8; ++i) {
            float4 v = x4[i];
            x[4*i+0] = v.x; x[4*i+1] = v.y; x[4*i+2] = v.z; x[4*i+3] = v.w;
        }
    }

    for (int t = 0; t < TT; ++t) {
        // e_n = dot(B[n,:], x)   -- 4 independent accumulator chains
        float e0 = 0.f, e1 = 0.f, e2 = 0.f, e3 = 0.f;
        #pragma unroll
        for (int s4 = 0; s4 < 8; ++s4) {
            e0 = fmaf(Brow[4*s4+0], x[4*s4+0], e0);
            e1 = fmaf(Brow[4*s4+1], x[4*s4+1], e1);
            e2 = fmaf(Brow[4*s4+2], x[4*s4+2], e2);
            e3 = fmaf(Brow[4*s4+3], x[4*s4+3], e3);
        }
        const float e = (e0 + e1) + (e2 + e3);

        float f = e * R;

        // S = sum over 64 lanes (butterfly -> all lanes hold S)
        float Ssum = f;
        #pragma unroll
        for (int off = 32; off; off >>= 1) Ssum += __shfl_xor(Ssum, off, 64);

        ll += __logf(Ssum);
        const float invS = __builtin_amdgcn_rcpf(Ssum);
        f *= invS;

        // store normalized fwd + running loglik
        op[t * 65 + lane] = f;
        if (lane == 0) op[t * 65 + 64] = ll;

        if (t + 1 < TT) {
            // prefetch x for t+1 (issue loads before the matvec)
            float4 xv[8];
            {
                const float4* xn = reinterpret_cast<const float4*>(xp + (size_t)(t + 1) * NSYM);
                #pragma unroll
                for (int i = 0; i < 8; ++i) xv[i] = xn[i];
            }

            // broadcast f, then R_next[n] = sum_i f[i] * A[i][n]
            fsh[t & 1][lane] = f;
            __syncthreads();
            float r0 = 0.f, r1 = 0.f, r2 = 0.f, r3 = 0.f;
            const float4* f4 = reinterpret_cast<const float4*>(fsh[t & 1]);
            #pragma unroll
            for (int i = 0; i < 16; ++i) {
                float4 v = f4[i];   // broadcast ds_read_b128
                r0 = fmaf(v.x, Acol[4*i+0], r0);
                r1 = fmaf(v.y, Acol[4*i+1], r1);
                r2 = fmaf(v.z, Acol[4*i+2], r2);
                r3 = fmaf(v.w, Acol[4*i+3], r3);
            }
            R = (r0 + r1) + (r2 + r3);

            #pragma unroll
            for (int i = 0; i < 8; ++i) {
                x[4*i+0] = xv[i].x; x[4*i+1] = xv[i].y;
                x[4*i+2] = xv[i].z; x[4*i+3] = xv[i].w;
            }
        }
    }
}

// ---------------------------------------------------------------------------
extern "C" void kernel_launch(void* const* d_in, const int* in_sizes, int n_in,
                              void* d_out, int out_size, void* d_ws, size_t ws_size,
                              hipStream_t stream) {
    const float* inputs = (const float*)d_in[0];  // [512,1024,32]
    const float* em     = (const float*)d_in[1];  // [64,32]
    const float* tr     = (const float*)d_in[2];  // [64,64]
    const float* ini    = (const float*)d_in[3];  // [64]
    float* out = (float*)d_out;                   // [512,1024,65]
    float* ws  = (float*)d_ws;                    // needs 6208 floats

    hmm_prep<<<1, 64, 0, stream>>>(em, tr, ini, ws);
    hmm_scan<<<BATCH, 64, 0, stream>>>(inputs, ws, out);
}

// Round 2
// 717.833 us; speedup vs baseline: 1.1296x; 1.1296x over previous
//
#include <hip/hip_runtime.h>

#define BATCH 512
#define TT    1024
#define NPAIR 512   // TT/2
#define NST   64
#define NSYM  32

// ---------------------------------------------------------------------------
// Prep: softmax(transition) -> ws[0..4095]   (A[i][j], row-major)
//       softmax(emission)   -> ws[4096..6143] (B[n][s], row-major)
//       softmax(init)       -> ws[6144..6207] (I[n])
// ---------------------------------------------------------------------------
__global__ __launch_bounds__(64) void hmm_prep(
    const float* __restrict__ em, const float* __restrict__ tr,
    const float* __restrict__ ini, float* __restrict__ ws)
{
    const int n = threadIdx.x;  // 0..63, one row per lane

    // A row n softmax (64 wide)
    {
        float a[64];
        float m = -1e30f;
        #pragma unroll
        for (int j = 0; j < 64; ++j) { a[j] = tr[n * 64 + j]; m = fmaxf(m, a[j]); }
        float s = 0.f;
        #pragma unroll
        for (int j = 0; j < 64; ++j) { a[j] = __expf(a[j] - m); s += a[j]; }
        const float inv = 1.f / s;
        #pragma unroll
        for (int j = 0; j < 64; ++j) ws[n * 64 + j] = a[j] * inv;
    }
    // B row n softmax (32 wide)
    {
        float b[32];
        float m = -1e30f;
        #pragma unroll
        for (int j = 0; j < 32; ++j) { b[j] = em[n * 32 + j]; m = fmaxf(m, b[j]); }
        float s = 0.f;
        #pragma unroll
        for (int j = 0; j < 32; ++j) { b[j] = __expf(b[j] - m); s += b[j]; }
        const float inv = 1.f / s;
        #pragma unroll
        for (int j = 0; j < 32; ++j) ws[4096 + n * 32 + j] = b[j] * inv;
    }
    // I softmax (cross-lane, 64 wide)
    {
        float v = ini[n];
        float m = v;
        #pragma unroll
        for (int off = 32; off; off >>= 1) m = fmaxf(m, __shfl_xor(m, off, 64));
        const float e = __expf(v - m);
        float s = e;
        #pragma unroll
        for (int off = 32; off; off >>= 1) s += __shfl_xor(s, off, 64);
        ws[6144 + n] = e / s;
    }
}

// ---------------------------------------------------------------------------
// Scan: one wave per batch element, lane = state.
//  Self-normalizing recurrence: h_{t+1} = (e_{t+1} o A^T h_t) * r_t,
//  r_t = rcp(sum(h_t)).  h_t == unnormalized forward u_t (bounded), so the
//  shuffle-reduce / rcp / log / stores are all OFF the h->h critical path.
//  x staged through an 8-pair LDS ring, cooperatively loaded (64 contiguous
//  floats = 2 time rows per coalesced load), 4 pairs (~8 steps) in flight.
// ---------------------------------------------------------------------------
__global__ __launch_bounds__(64) void hmm_scan(
    const float* __restrict__ inputs, const float* __restrict__ ws,
    float* __restrict__ out)
{
    const int b    = blockIdx.x;
    const int lane = threadIdx.x;  // 0..63 = state

    const float* __restrict__ A  = ws;          // [64][64]
    const float* __restrict__ Bm = ws + 4096;   // [64][32]
    const float* __restrict__ Iv = ws + 6144;   // [64]

    // A column `lane` into registers: Acol[i] = A[i][lane]
    float Acol[64];
    #pragma unroll
    for (int i = 0; i < 64; ++i) Acol[i] = A[i * 64 + lane];

    // B row `lane` into registers
    float Brow[32];
    {
        const float4* B4 = reinterpret_cast<const float4*>(Bm + lane * 32);
        #pragma unroll
        for (int i = 0; i < 8; ++i) {
            float4 v = B4[i];
            Brow[4*i+0] = v.x; Brow[4*i+1] = v.y;
            Brow[4*i+2] = v.z; Brow[4*i+3] = v.w;
        }
    }
    const float Iv_l = Iv[lane];

    __shared__ float xlds[8 * 64];   // 8-pair ring; pair P at slot (P&7)*64
    __shared__ float hsh[2][64];     // double-buffered h broadcast

    const float* __restrict__ xp = inputs + (size_t)b * (TT * NSYM);
    float* __restrict__ op       = out    + (size_t)b * (TT * 65);

    // Prologue: pairs 0..3 directly into LDS
    #pragma unroll
    for (int k = 0; k < 4; ++k) {
        float v = xp[k * 64 + lane];
        xlds[k * 64 + lane] = v;
    }
    // Pending ring: pairs 4..7 in flight in VGPRs
    float xpend[4];
    #pragma unroll
    for (int k = 0; k < 4; ++k) xpend[k] = xp[(4 + k) * 64 + lane];

    float rp = 1.f;   // r_{t-1}
    float ll = 0.f;

    auto body = [&](int t) {
        // emission dot: x row t from LDS ring (broadcast b128 reads)
        const float* xr = xlds + ((t >> 1) & 7) * 64 + (t & 1) * 32;
        const float4* x4 = reinterpret_cast<const float4*>(xr);
        float e0 = 0.f, e1 = 0.f, e2 = 0.f, e3 = 0.f;
        #pragma unroll
        for (int i = 0; i < 8; ++i) {
            float4 v = x4[i];
            e0 = fmaf(Brow[4*i+0], v.x, e0);
            e1 = fmaf(Brow[4*i+1], v.y, e1);
            e2 = fmaf(Brow[4*i+2], v.z, e2);
            e3 = fmaf(Brow[4*i+3], v.w, e3);
        }
        const float e = (e0 + e1) + (e2 + e3);

        // matvec: v[n] = sum_i h_prev[i] * A[i][n]  (h_prev in hsh[(t+1)&1])
        const float4* f4 = reinterpret_cast<const float4*>(hsh[(t + 1) & 1]);
        float r0 = 0.f, r1 = 0.f, r2 = 0.f, r3 = 0.f;
        #pragma unroll
        for (int i = 0; i < 16; ++i) {
            float4 v = f4[i];
            r0 = fmaf(v.x, Acol[4*i+0], r0);
            r1 = fmaf(v.y, Acol[4*i+1], r1);
            r2 = fmaf(v.z, Acol[4*i+2], r2);
            r3 = fmaf(v.w, Acol[4*i+3], r3);
        }
        const float mv = (r0 + r1) + (r2 + r3);

        const float hsrc = (t == 0) ? Iv_l : mv * rp;   // t=0: R = I, r=1
        const float h = e * hsrc;                        // h == u_t (unnormalized)
        hsh[t & 1][lane] = h;      // EARLY: next body's matvec depends on this

        // off-critical-path: sum, rcp, log, stores
        float S = h;
        #pragma unroll
        for (int off = 32; off; off >>= 1) S += __shfl_xor(S, off, 64);
        const float r = __builtin_amdgcn_rcpf(S);
        ll += __logf(S);
        op[t * 65 + lane] = h * r;
        if (lane == 0) op[t * 65 + 64] = ll;
        rp = r;
    };

    for (int PP = 0; PP < 128; ++PP) {
        #pragma unroll
        for (int j = 0; j < 4; ++j) {           // j static -> xpend[j] static
            const int P = PP * 4 + j;
            // stage pair P+4 (loaded 4 pairs ago) into the LDS ring
            xlds[((P + 4) & 7) * 64 + lane] = xpend[j];
            // refill: issue load for pair P+8 (clamped; tail re-loads pair 511)
            int Pl = P + 8; if (Pl > NPAIR - 1) Pl = NPAIR - 1;
            xpend[j] = xp[Pl * 64 + lane];

            body(2 * P);
            body(2 * P + 1);
        }
    }
}

// ---------------------------------------------------------------------------
extern "C" void kernel_launch(void* const* d_in, const int* in_sizes, int n_in,
                              void* d_out, int out_size, void* d_ws, size_t ws_size,
                              hipStream_t stream) {
    const float* inputs = (const float*)d_in[0];  // [512,1024,32]
    const float* em     = (const float*)d_in[1];  // [64,32]
    const float* tr     = (const float*)d_in[2];  // [64,64]
    const float* ini    = (const float*)d_in[3];  // [64]
    float* out = (float*)d_out;                   // [512,1024,65]
    float* ws  = (float*)d_ws;                    // needs 6208 floats

    hmm_prep<<<1, 64, 0, stream>>>(em, tr, ini, ws);
    hmm_scan<<<BATCH, 64, 0, stream>>>(inputs, ws, out);
}

// Round 3
// 578.009 us; speedup vs baseline: 1.4028x; 1.2419x over previous
//
#include <hip/hip_runtime.h>

#define BATCH 512
#define TT    1024
#define NPAIR 512   // TT/2
#define NST   64
#define NSYM  32
#define LN2F  0.69314718055994530942f

// ---------------------------------------------------------------------------
// Prep: softmax(transition) -> ws[0..4095]   (A[i][j], row-major)
//       softmax(emission)   -> ws[4096..6143] (B[n][s], row-major)
//       softmax(init)       -> ws[6144..6207] (I[n])
// ---------------------------------------------------------------------------
__global__ __launch_bounds__(64) void hmm_prep(
    const float* __restrict__ em, const float* __restrict__ tr,
    const float* __restrict__ ini, float* __restrict__ ws)
{
    const int n = threadIdx.x;  // 0..63, one row per lane

    {
        float a[64];
        float m = -1e30f;
        #pragma unroll
        for (int j = 0; j < 64; ++j) { a[j] = tr[n * 64 + j]; m = fmaxf(m, a[j]); }
        float s = 0.f;
        #pragma unroll
        for (int j = 0; j < 64; ++j) { a[j] = __expf(a[j] - m); s += a[j]; }
        const float inv = 1.f / s;
        #pragma unroll
        for (int j = 0; j < 64; ++j) ws[n * 64 + j] = a[j] * inv;
    }
    {
        float b[32];
        float m = -1e30f;
        #pragma unroll
        for (int j = 0; j < 32; ++j) { b[j] = em[n * 32 + j]; m = fmaxf(m, b[j]); }
        float s = 0.f;
        #pragma unroll
        for (int j = 0; j < 32; ++j) { b[j] = __expf(b[j] - m); s += b[j]; }
        const float inv = 1.f / s;
        #pragma unroll
        for (int j = 0; j < 32; ++j) ws[4096 + n * 32 + j] = b[j] * inv;
    }
    {
        float v = ini[n];
        float m = v;
        #pragma unroll
        for (int off = 32; off; off >>= 1) m = fmaxf(m, __shfl_xor(m, off, 64));
        const float e = __expf(v - m);
        float s = e;
        #pragma unroll
        for (int off = 32; off; off >>= 1) s += __shfl_xor(s, off, 64);
        ws[6144 + n] = e / s;
    }
}

// ---------------------------------------------------------------------------
// Scan: one wave per batch element, lane = state.
//  UNNORMALIZED recurrence: h_t = sc_t * e_t o (A^T h_{t-1}).
//  sc_t = exact power of 2 from exponent of h_{t-1}[0] (stale feedback keeps
//  h ~ O(1)); integer Esum compensates exactly:  u_t = h_t * 2^Esum.
//  Outputs are pure functions of h_t:  f_t = h_t/sum(h_t),
//  ll_t = log(sum(h_t)) + Esum*ln2  -- the shuffle-reduce/rcp/log/store
//  pipeline runs one step delayed and never feeds the recurrence.
//  Fully branchless body (single BB) so the scheduler interleaves the
//  off-path shuffle chain under the matvec's LDS waits.
// ---------------------------------------------------------------------------
__global__ __launch_bounds__(64) void hmm_scan(
    const float* __restrict__ inputs, const float* __restrict__ ws,
    float* __restrict__ out)
{
    const int b    = blockIdx.x;
    const int lane = threadIdx.x;  // 0..63 = state

    const float* __restrict__ A  = ws;          // [64][64]
    const float* __restrict__ Bm = ws + 4096;   // [64][32]
    const float* __restrict__ Iv = ws + 6144;   // [64]

    float Acol[64];
    #pragma unroll
    for (int i = 0; i < 64; ++i) Acol[i] = A[i * 64 + lane];

    float Brow[32];
    {
        const float4* B4 = reinterpret_cast<const float4*>(Bm + lane * 32);
        #pragma unroll
        for (int i = 0; i < 8; ++i) {
            float4 v = B4[i];
            Brow[4*i+0] = v.x; Brow[4*i+1] = v.y;
            Brow[4*i+2] = v.z; Brow[4*i+3] = v.w;
        }
    }
    const float Iv_l = Iv[lane];

    __shared__ float xlds[8 * 64];   // 8-pair ring; pair P at slot (P&7)*64
    __shared__ float hsh[2][64];     // double-buffered h broadcast

    const float* __restrict__ xp = inputs + (size_t)b * (TT * NSYM);
    float* __restrict__ op       = out    + (size_t)b * (TT * 65);

    // Prologue: pairs 0..3 into LDS; pairs 4..7 pending in VGPRs
    #pragma unroll
    for (int k = 0; k < 4; ++k) xlds[k * 64 + lane] = xp[k * 64 + lane];
    float xpend[4];
    #pragma unroll
    for (int k = 0; k < 4; ++k) xpend[k] = xp[(4 + k) * 64 + lane];

    float hprev = 0.f;
    int   Esum  = 0;

    auto body = [&](int t) {
        const bool is0 = (t == 0);

        // ---- off-path: power-of-2 scale feedback from h_{t-1}[0] ----
        const unsigned bits = __builtin_amdgcn_readfirstlane(__float_as_uint(hprev));
        int ex = (int)((bits >> 23) & 255u);
        ex = ex < 1 ? 1 : (ex > 253 ? 253 : ex);
        float sc = __uint_as_float((unsigned)(254 - ex) << 23);   // 2^(127-ex)
        sc = is0 ? 1.0f : sc;
        const int EsumPrev = Esum;
        Esum += is0 ? 0 : (ex - 127);

        // ---- off-path: reduce of h_{t-1} (feeds only the delayed outputs) ----
        float S = hprev;
        #pragma unroll
        for (int off = 32; off; off >>= 1) S += __shfl_xor(S, off, 64);

        // ---- emission dot for t (x from LDS ring) ----
        const float* xr = xlds + ((t >> 1) & 7) * 64 + (t & 1) * 32;
        const float4* x4 = reinterpret_cast<const float4*>(xr);
        float e0 = 0.f, e1 = 0.f, e2 = 0.f, e3 = 0.f;
        #pragma unroll
        for (int i = 0; i < 8; ++i) {
            float4 v = x4[i];
            e0 = fmaf(Brow[4*i+0], v.x, e0);
            e1 = fmaf(Brow[4*i+1], v.y, e1);
            e2 = fmaf(Brow[4*i+2], v.z, e2);
            e3 = fmaf(Brow[4*i+3], v.w, e3);
        }
        const float e = (((e0 + e1) + (e2 + e3))) * sc;

        // ---- critical path: matvec on h_{t-1} via LDS broadcast ----
        const float4* f4 = reinterpret_cast<const float4*>(hsh[(t + 1) & 1]);
        float r0 = 0.f, r1 = 0.f, r2 = 0.f, r3 = 0.f;
        #pragma unroll
        for (int i = 0; i < 16; ++i) {
            float4 v = f4[i];
            r0 = fmaf(v.x, Acol[4*i+0], r0);
            r1 = fmaf(v.y, Acol[4*i+1], r1);
            r2 = fmaf(v.z, Acol[4*i+2], r2);
            r3 = fmaf(v.w, Acol[4*i+3], r3);
        }
        float mv = (r0 + r1) + (r2 + r3);
        mv = is0 ? Iv_l : mv;        // t=0: R = I (LDS garbage discarded)

        const float h = e * mv;      // h_t, kept ~O(1) by sc
        hsh[t & 1][lane] = h;        // EARLY: next body's matvec needs this

        // ---- delayed outputs for step t-1 (body 0 writes junk to row 0,
        //      body 1 overwrites it -- deterministic) ----
        const int tp = is0 ? 0 : (t - 1);
        const float r = __builtin_amdgcn_rcpf(S);
        op[tp * 65 + lane] = hprev * r;
        if (lane == 0) op[tp * 65 + 64] = __logf(S) + (float)EsumPrev * LN2F;

        hprev = h;
    };

    for (int PP = 0; PP < 128; ++PP) {
        #pragma unroll
        for (int j = 0; j < 4; ++j) {           // j static -> xpend[j] static
            const int P = PP * 4 + j;
            xlds[((P + 4) & 7) * 64 + lane] = xpend[j];
            int Pl = P + 8; if (Pl > NPAIR - 1) Pl = NPAIR - 1;
            xpend[j] = xp[Pl * 64 + lane];

            body(2 * P);
            body(2 * P + 1);
        }
    }

    // Epilogue: outputs for t = 1023
    {
        float S = hprev;
        #pragma unroll
        for (int off = 32; off; off >>= 1) S += __shfl_xor(S, off, 64);
        const float r = __builtin_amdgcn_rcpf(S);
        op[1023 * 65 + lane] = hprev * r;
        if (lane == 0) op[1023 * 65 + 64] = __logf(S) + (float)Esum * LN2F;
    }
}

// ---------------------------------------------------------------------------
extern "C" void kernel_launch(void* const* d_in, const int* in_sizes, int n_in,
                              void* d_out, int out_size, void* d_ws, size_t ws_size,
                              hipStream_t stream) {
    const float* inputs = (const float*)d_in[0];  // [512,1024,32]
    const float* em     = (const float*)d_in[1];  // [64,32]
    const float* tr     = (const float*)d_in[2];  // [64,64]
    const float* ini    = (const float*)d_in[3];  // [64]
    float* out = (float*)d_out;                   // [512,1024,65]
    float* ws  = (float*)d_ws;                    // needs 6208 floats

    hmm_prep<<<1, 64, 0, stream>>>(em, tr, ini, ws);
    hmm_scan<<<BATCH, 64, 0, stream>>>(inputs, ws, out);
}

// Round 4
// 500.000 us; speedup vs baseline: 1.6217x; 1.1560x over previous
//
#include <hip/hip_runtime.h>

#define BATCH 512
#define TT    1024
#define NPAIR 512   // TT/2
#define NST   64
#define NSYM  32
#define LN2F  0.69314718055994530942f

// ---------------------------------------------------------------------------
// Wave64 sum reduction on the VALU only (DPP row ops, rocPRIM pattern).
// bound_ctrl=1: out-of-range source lanes contribute 0. Total lands in lane 63.
// NO DS-pipe ops (unlike __shfl_xor -> ds_bpermute).
// ---------------------------------------------------------------------------
template <int CTRL>
__device__ __forceinline__ float dpp_add(float x) {
    int y = __builtin_amdgcn_update_dpp(0, __float_as_int(x), CTRL, 0xf, 0xf, true);
    return x + __int_as_float(y);
}
__device__ __forceinline__ float wave64_sum_sgpr(float x) {
    x = dpp_add<0x111>(x);   // row_shr:1
    x = dpp_add<0x112>(x);   // row_shr:2
    x = dpp_add<0x114>(x);   // row_shr:4
    x = dpp_add<0x118>(x);   // row_shr:8   -> lane 15 of each row16 = row sum
    x = dpp_add<0x142>(x);   // row_bcast:15 -> lane31 = rows0+1, lane63 = rows2+3
    x = dpp_add<0x143>(x);   // row_bcast:31 -> lane63 = total
    return __int_as_float(__builtin_amdgcn_readlane(__float_as_int(x), 63));
}

// ---------------------------------------------------------------------------
// Prep: softmax(transition) -> ws[0..4095]   (A[i][j], row-major)
//       softmax(emission)   -> ws[4096..6143] (B[n][s], row-major)
//       softmax(init)       -> ws[6144..6207] (I[n])
// ---------------------------------------------------------------------------
__global__ __launch_bounds__(64) void hmm_prep(
    const float* __restrict__ em, const float* __restrict__ tr,
    const float* __restrict__ ini, float* __restrict__ ws)
{
    const int n = threadIdx.x;  // 0..63, one row per lane

    {
        float a[64];
        float m = -1e30f;
        #pragma unroll
        for (int j = 0; j < 64; ++j) { a[j] = tr[n * 64 + j]; m = fmaxf(m, a[j]); }
        float s = 0.f;
        #pragma unroll
        for (int j = 0; j < 64; ++j) { a[j] = __expf(a[j] - m); s += a[j]; }
        const float inv = 1.f / s;
        #pragma unroll
        for (int j = 0; j < 64; ++j) ws[n * 64 + j] = a[j] * inv;
    }
    {
        float b[32];
        float m = -1e30f;
        #pragma unroll
        for (int j = 0; j < 32; ++j) { b[j] = em[n * 32 + j]; m = fmaxf(m, b[j]); }
        float s = 0.f;
        #pragma unroll
        for (int j = 0; j < 32; ++j) { b[j] = __expf(b[j] - m); s += b[j]; }
        const float inv = 1.f / s;
        #pragma unroll
        for (int j = 0; j < 32; ++j) ws[4096 + n * 32 + j] = b[j] * inv;
    }
    {
        float v = ini[n];
        float m = v;
        #pragma unroll
        for (int off = 32; off; off >>= 1) m = fmaxf(m, __shfl_xor(m, off, 64));
        const float e = __expf(v - m);
        float s = e;
        #pragma unroll
        for (int off = 32; off; off >>= 1) s += __shfl_xor(s, off, 64);
        ws[6144 + n] = e / s;
    }
}

// ---------------------------------------------------------------------------
// Scan: one wave per batch element, lane = state.
//  UNNORMALIZED recurrence: h_t = sc_t * e_t o (A^T h_{t-1}), sc_t an exact
//  power of 2 from the (one-step-stale) exponent of h_{t-1}[0]; integer Esum
//  compensates exactly. Outputs (f_t, ll_t) are pure functions of h_t and are
//  emitted one step delayed. The per-step sum uses the DPP VALU reduction --
//  the DS pipe carries ONLY the h broadcast + x ring.
// ---------------------------------------------------------------------------
__global__ __launch_bounds__(64) void hmm_scan(
    const float* __restrict__ inputs, const float* __restrict__ ws,
    float* __restrict__ out)
{
    const int b    = blockIdx.x;
    const int lane = threadIdx.x;  // 0..63 = state

    const float* __restrict__ A  = ws;          // [64][64]
    const float* __restrict__ Bm = ws + 4096;   // [64][32]
    const float* __restrict__ Iv = ws + 6144;   // [64]

    float Acol[64];
    #pragma unroll
    for (int i = 0; i < 64; ++i) Acol[i] = A[i * 64 + lane];

    float Brow[32];
    {
        const float4* B4 = reinterpret_cast<const float4*>(Bm + lane * 32);
        #pragma unroll
        for (int i = 0; i < 8; ++i) {
            float4 v = B4[i];
            Brow[4*i+0] = v.x; Brow[4*i+1] = v.y;
            Brow[4*i+2] = v.z; Brow[4*i+3] = v.w;
        }
    }
    const float Iv_l = Iv[lane];

    __shared__ float xlds[8 * 64];   // 8-pair ring; pair P at slot (P&7)*64
    __shared__ float hsh[2][64];     // double-buffered h broadcast

    const float* __restrict__ xp = inputs + (size_t)b * (TT * NSYM);
    float* __restrict__ op       = out    + (size_t)b * (TT * 65);

    // Prologue: pairs 0..3 into LDS; pairs 4..7 pending in VGPRs
    #pragma unroll
    for (int k = 0; k < 4; ++k) xlds[k * 64 + lane] = xp[k * 64 + lane];
    float xpend[4];
    #pragma unroll
    for (int k = 0; k < 4; ++k) xpend[k] = xp[(4 + k) * 64 + lane];

    float hprev = 0.f;
    int   Esum  = 0;

    auto body = [&](int t) {
        const bool is0 = (t == 0);

        // ---- off-path (VALU only): scale feedback + sum of h_{t-1} ----
        const unsigned bits = __builtin_amdgcn_readfirstlane(__float_as_uint(hprev));
        int ex = (int)((bits >> 23) & 255u);
        ex = ex < 1 ? 1 : (ex > 253 ? 253 : ex);
        float sc = __uint_as_float((unsigned)(254 - ex) << 23);   // 2^(127-ex)
        sc = is0 ? 1.0f : sc;
        const int EsumPrev = Esum;
        Esum += is0 ? 0 : (ex - 127);

        const float S = wave64_sum_sgpr(hprev);   // DPP, no DS ops

        // ---- emission dot for t (x from LDS ring, broadcast b128 reads) ----
        const float* xr = xlds + ((t >> 1) & 7) * 64 + (t & 1) * 32;
        const float4* x4 = reinterpret_cast<const float4*>(xr);
        float e0 = 0.f, e1 = 0.f, e2 = 0.f, e3 = 0.f;
        #pragma unroll
        for (int i = 0; i < 8; ++i) {
            float4 v = x4[i];
            e0 = fmaf(Brow[4*i+0], v.x, e0);
            e1 = fmaf(Brow[4*i+1], v.y, e1);
            e2 = fmaf(Brow[4*i+2], v.z, e2);
            e3 = fmaf(Brow[4*i+3], v.w, e3);
        }
        const float e = (((e0 + e1) + (e2 + e3))) * sc;

        // ---- critical path: matvec on h_{t-1} via LDS broadcast ----
        // 8 accumulator chains: dependent-FMA tail is 8 deep, not 16
        const float4* f4 = reinterpret_cast<const float4*>(hsh[(t + 1) & 1]);
        float r0 = 0.f, r1 = 0.f, r2 = 0.f, r3 = 0.f;
        float r4 = 0.f, r5 = 0.f, r6 = 0.f, r7 = 0.f;
        #pragma unroll
        for (int i = 0; i < 8; ++i) {
            float4 va = f4[2*i];
            float4 vb = f4[2*i+1];
            r0 = fmaf(va.x, Acol[8*i+0], r0);
            r1 = fmaf(va.y, Acol[8*i+1], r1);
            r2 = fmaf(va.z, Acol[8*i+2], r2);
            r3 = fmaf(va.w, Acol[8*i+3], r3);
            r4 = fmaf(vb.x, Acol[8*i+4], r4);
            r5 = fmaf(vb.y, Acol[8*i+5], r5);
            r6 = fmaf(vb.z, Acol[8*i+6], r6);
            r7 = fmaf(vb.w, Acol[8*i+7], r7);
        }
        float mv = ((r0 + r1) + (r2 + r3)) + ((r4 + r5) + (r6 + r7));
        mv = is0 ? Iv_l : mv;        // t=0: R = I (LDS garbage discarded)

        const float h = e * mv;      // h_t, kept ~O(1) by sc
        hsh[t & 1][lane] = h;        // EARLY: next body's matvec needs this

        // ---- delayed outputs for step t-1 (t=0 writes junk to row 0,
        //      overwritten at t=1 -- deterministic) ----
        const int tp = is0 ? 0 : (t - 1);
        const float r = __builtin_amdgcn_rcpf(S);
        op[tp * 65 + lane] = hprev * r;
        if (lane == 0) op[tp * 65 + 64] = __logf(S) + (float)EsumPrev * LN2F;

        hprev = h;
    };

    for (int PP = 0; PP < 128; ++PP) {
        #pragma unroll
        for (int j = 0; j < 4; ++j) {           // j static -> xpend[j] static
            const int P = PP * 4 + j;
            xlds[((P + 4) & 7) * 64 + lane] = xpend[j];
            int Pl = P + 8; if (Pl > NPAIR - 1) Pl = NPAIR - 1;
            xpend[j] = xp[Pl * 64 + lane];

            body(2 * P);
            body(2 * P + 1);
        }
    }

    // Epilogue: outputs for t = 1023
    {
        const float S = wave64_sum_sgpr(hprev);
        const float r = __builtin_amdgcn_rcpf(S);
        op[1023 * 65 + lane] = hprev * r;
        if (lane == 0) op[1023 * 65 + 64] = __logf(S) + (float)Esum * LN2F;
    }
}

// ---------------------------------------------------------------------------
extern "C" void kernel_launch(void* const* d_in, const int* in_sizes, int n_in,
                              void* d_out, int out_size, void* d_ws, size_t ws_size,
                              hipStream_t stream) {
    const float* inputs = (const float*)d_in[0];  // [512,1024,32]
    const float* em     = (const float*)d_in[1];  // [64,32]
    const float* tr     = (const float*)d_in[2];  // [64,64]
    const float* ini    = (const float*)d_in[3];  // [64]
    float* out = (float*)d_out;                   // [512,1024,65]
    float* ws  = (float*)d_ws;                    // needs 6208 floats

    hmm_prep<<<1, 64, 0, stream>>>(em, tr, ini, ws);
    hmm_scan<<<BATCH, 64, 0, stream>>>(inputs, ws, out);
}

// Round 5
// 433.812 us; speedup vs baseline: 1.8691x; 1.1526x over previous
//
#include <hip/hip_runtime.h>

#define BATCH 512
#define TT    1024
#define NST   64
#define NSYM  32
#define LN2F  0.69314718055994530942f

// ---------------------------------------------------------------------------
// Wave64 sum reduction on the VALU only (DPP row ops, rocPRIM pattern).
// bound_ctrl=1: out-of-range source lanes contribute 0. Total lands in lane 63.
// ---------------------------------------------------------------------------
template <int CTRL>
__device__ __forceinline__ float dpp_add(float x) {
    int y = __builtin_amdgcn_update_dpp(0, __float_as_int(x), CTRL, 0xf, 0xf, true);
    return x + __int_as_float(y);
}
__device__ __forceinline__ float wave64_sum_sgpr(float x) {
    x = dpp_add<0x111>(x);   // row_shr:1
    x = dpp_add<0x112>(x);   // row_shr:2
    x = dpp_add<0x114>(x);   // row_shr:4
    x = dpp_add<0x118>(x);   // row_shr:8
    x = dpp_add<0x142>(x);   // row_bcast:15
    x = dpp_add<0x143>(x);   // row_bcast:31 -> lane63 = total
    return __int_as_float(__builtin_amdgcn_readlane(__float_as_int(x), 63));
}

// ---------------------------------------------------------------------------
// Prep: softmax(transition) -> ws[0..4095]   (A[i][j], row-major)
//       softmax(emission)   -> ws[4096..6143] (B[n][s], row-major)
//       softmax(init)       -> ws[6144..6207] (I[n])
// ---------------------------------------------------------------------------
__global__ __launch_bounds__(64) void hmm_prep(
    const float* __restrict__ em, const float* __restrict__ tr,
    const float* __restrict__ ini, float* __restrict__ ws)
{
    const int n = threadIdx.x;

    {
        float a[64];
        float m = -1e30f;
        #pragma unroll
        for (int j = 0; j < 64; ++j) { a[j] = tr[n * 64 + j]; m = fmaxf(m, a[j]); }
        float s = 0.f;
        #pragma unroll
        for (int j = 0; j < 64; ++j) { a[j] = __expf(a[j] - m); s += a[j]; }
        const float inv = 1.f / s;
        #pragma unroll
        for (int j = 0; j < 64; ++j) ws[n * 64 + j] = a[j] * inv;
    }
    {
        float bv[32];
        float m = -1e30f;
        #pragma unroll
        for (int j = 0; j < 32; ++j) { bv[j] = em[n * 32 + j]; m = fmaxf(m, bv[j]); }
        float s = 0.f;
        #pragma unroll
        for (int j = 0; j < 32; ++j) { bv[j] = __expf(bv[j] - m); s += bv[j]; }
        const float inv = 1.f / s;
        #pragma unroll
        for (int j = 0; j < 32; ++j) ws[4096 + n * 32 + j] = bv[j] * inv;
    }
    {
        float v = ini[n];
        float m = v;
        #pragma unroll
        for (int off = 32; off; off >>= 1) m = fmaxf(m, __shfl_xor(m, off, 64));
        const float e = __expf(v - m);
        float s = e;
        #pragma unroll
        for (int off = 32; off; off >>= 1) s += __shfl_xor(s, off, 64);
        ws[6144 + n] = e / s;
    }
}

// ---------------------------------------------------------------------------
// Emission pass: E[b][t][n] = dot(B[n,:], x[b,t,:])  stored INTO d_out's fwd
// slots (op[t*65 + n]).  The scan reads E row t at step t and overwrites row
// t-1 at step t, so the storage never collides.  Massively parallel,
// memory-bound (~200 MB).
// ---------------------------------------------------------------------------
__global__ __launch_bounds__(256) void hmm_emit(
    const float* __restrict__ inputs, const float* __restrict__ ws,
    float* __restrict__ out)
{
    const int b    = blockIdx.x >> 5;
    const int chk  = blockIdx.x & 31;    // 32 t-rows per block
    const int tid  = threadIdx.x;
    const int lane = tid & 63;
    const int w    = tid >> 6;

    __shared__ float xs[32 * 32];
    const float* __restrict__ xp = inputs + ((size_t)b * TT + (size_t)chk * 32) * NSYM;
    reinterpret_cast<float4*>(xs)[tid] = reinterpret_cast<const float4*>(xp)[tid];

    float Brow[32];
    {
        const float4* B4 = reinterpret_cast<const float4*>(ws + 4096 + lane * 32);
        #pragma unroll
        for (int i = 0; i < 8; ++i) {
            float4 v = B4[i];
            Brow[4*i+0] = v.x; Brow[4*i+1] = v.y;
            Brow[4*i+2] = v.z; Brow[4*i+3] = v.w;
        }
    }
    __syncthreads();

    float* __restrict__ op = out + ((size_t)b * TT + (size_t)chk * 32) * 65;
    #pragma unroll
    for (int r = 0; r < 8; ++r) {
        const int trow = w * 8 + r;
        const float4* x4 = reinterpret_cast<const float4*>(xs + trow * 32);
        float e0 = 0.f, e1 = 0.f, e2 = 0.f, e3 = 0.f;
        #pragma unroll
        for (int i = 0; i < 8; ++i) {
            float4 v = x4[i];
            e0 = fmaf(Brow[4*i+0], v.x, e0);
            e1 = fmaf(Brow[4*i+1], v.y, e1);
            e2 = fmaf(Brow[4*i+2], v.z, e2);
            e3 = fmaf(Brow[4*i+3], v.w, e3);
        }
        op[(size_t)trow * 65 + lane] = (e0 + e1) + (e2 + e3);
    }
}

// ---------------------------------------------------------------------------
// Scan: 2 waves per block (-> different SIMDs), one chain per wave,
// lane = state.  Per step the wave does ONLY:
//   matvec (16 broadcast ds_read_b128 + 64 FMA), scale feedback (SALU),
//   DPP sum, delayed outputs, one E-row load into an 8-deep register ring.
// Unnormalized recurrence h_t = (E_t o A^T h_{t-1}) * sc_t with exact
// power-of-2 sc from the stale exponent of h_{t-1}[0]; Esum compensates.
// ---------------------------------------------------------------------------
__global__ __launch_bounds__(128) void hmm_scan(
    const float* __restrict__ ws, float* __restrict__ out)
{
    const int w    = threadIdx.x >> 6;
    const int lane = threadIdx.x & 63;
    const int b    = blockIdx.x * 2 + w;

    float Acol[64];
    #pragma unroll
    for (int i = 0; i < 64; ++i) Acol[i] = ws[i * 64 + lane];
    const float Iv_l = ws[6144 + lane];

    __shared__ float hsh[2][2][64];   // [wave][buf][state]

    float* __restrict__ op = out + (size_t)b * (TT * 65);

    // E ring: rows 0..7
    float eR[8];
    #pragma unroll
    for (int k = 0; k < 8; ++k) eR[k] = op[k * 65 + lane];

    float hprev = 0.f;
    int   Esum  = 0;

    auto body = [&](int t, int j, bool refill) {
        const bool is0 = (t == 0);

        // ---- scale feedback (scalar pipe; resolves under the matvec) ----
        const unsigned bits = __builtin_amdgcn_readfirstlane(__float_as_uint(hprev));
        int ex = (int)((bits >> 23) & 255u);
        ex = ex < 1 ? 1 : (ex > 253 ? 253 : ex);
        float sc = __uint_as_float((unsigned)(254 - ex) << 23);   // 2^(127-ex)
        sc = is0 ? 1.0f : sc;
        const int EsumPrev = Esum;
        Esum += is0 ? 0 : (ex - 127);

        // ---- VALU-only reduce of h_{t-1} (feeds only delayed outputs) ----
        const float S = wave64_sum_sgpr(hprev);

        // ---- critical path: matvec via LDS broadcast ----
        const float4* f4 = reinterpret_cast<const float4*>(hsh[w][(t + 1) & 1]);
        float r0 = 0.f, r1 = 0.f, r2 = 0.f, r3 = 0.f;
        float r4 = 0.f, r5 = 0.f, r6 = 0.f, r7 = 0.f;
        #pragma unroll
        for (int i = 0; i < 8; ++i) {
            float4 va = f4[2*i];
            float4 vb = f4[2*i+1];
            r0 = fmaf(va.x, Acol[8*i+0], r0);
            r1 = fmaf(va.y, Acol[8*i+1], r1);
            r2 = fmaf(va.z, Acol[8*i+2], r2);
            r3 = fmaf(va.w, Acol[8*i+3], r3);
            r4 = fmaf(vb.x, Acol[8*i+4], r4);
            r5 = fmaf(vb.y, Acol[8*i+5], r5);
            r6 = fmaf(vb.z, Acol[8*i+6], r6);
            r7 = fmaf(vb.w, Acol[8*i+7], r7);
        }
        float mv = ((r0 + r1) + (r2 + r3)) + ((r4 + r5) + (r6 + r7));
        mv = is0 ? Iv_l : mv;

        const float h = (eR[j] * mv) * sc;
        hsh[w][t & 1][lane] = h;       // next step's matvec input

        // refill E ring with row t+8 (main loop only; t+8 <= 1023 there)
        if (refill) eR[j] = op[(t + 8) * 65 + lane];

        // ---- delayed outputs for step t-1 (t=0 writes junk to row 0,
        //      overwritten at t=1; row 0's E was consumed in the prologue) ----
        const int tp = is0 ? 0 : (t - 1);
        const float r = __builtin_amdgcn_rcpf(S);
        op[tp * 65 + lane] = hprev * r;
        if (lane == 0) op[tp * 65 + 64] = __logf(S) + (float)EsumPrev * LN2F;

        hprev = h;
    };

    for (int Q = 0; Q < 127; ++Q) {
        #pragma unroll
        for (int j = 0; j < 8; ++j) body(Q * 8 + j, j, true);
    }
    #pragma unroll
    for (int j = 0; j < 8; ++j) body(1016 + j, j, false);   // tail: no refill

    // Epilogue: outputs for t = 1023
    {
        const float S = wave64_sum_sgpr(hprev);
        const float r = __builtin_amdgcn_rcpf(S);
        op[1023 * 65 + lane] = hprev * r;
        if (lane == 0) op[1023 * 65 + 64] = __logf(S) + (float)Esum * LN2F;
    }
}

// ---------------------------------------------------------------------------
extern "C" void kernel_launch(void* const* d_in, const int* in_sizes, int n_in,
                              void* d_out, int out_size, void* d_ws, size_t ws_size,
                              hipStream_t stream) {
    const float* inputs = (const float*)d_in[0];  // [512,1024,32]
    const float* em     = (const float*)d_in[1];  // [64,32]
    const float* tr     = (const float*)d_in[2];  // [64,64]
    const float* ini    = (const float*)d_in[3];  // [64]
    float* out = (float*)d_out;                   // [512,1024,65]
    float* ws  = (float*)d_ws;                    // 6208 floats used

    hmm_prep<<<1, 64, 0, stream>>>(em, tr, ini, ws);
    hmm_emit<<<BATCH * (TT / 32), 256, 0, stream>>>(inputs, ws, out);
    hmm_scan<<<BATCH / 2, 128, 0, stream>>>(ws, out);
}

// Round 6
// 344.318 us; speedup vs baseline: 2.3549x; 1.2599x over previous
//
#include <hip/hip_runtime.h>

#define BATCH 512
#define TT    1024
#define NST   64
#define NSYM  32
#define LN2F  0.69314718055994530942f

typedef _Float16 half2v __attribute__((ext_vector_type(2)));

// ---------------------------------------------------------------------------
// Wave64 sum reduction on the VALU only (DPP row ops, rocPRIM pattern).
// bound_ctrl=1: out-of-range source lanes contribute 0. Total lands in lane 63.
// ---------------------------------------------------------------------------
template <int CTRL>
__device__ __forceinline__ float dpp_add(float x) {
    int y = __builtin_amdgcn_update_dpp(0, __float_as_int(x), CTRL, 0xf, 0xf, true);
    return x + __int_as_float(y);
}
__device__ __forceinline__ float wave64_sum_sgpr(float x) {
    x = dpp_add<0x111>(x);   // row_shr:1
    x = dpp_add<0x112>(x);   // row_shr:2
    x = dpp_add<0x114>(x);   // row_shr:4
    x = dpp_add<0x118>(x);   // row_shr:8
    x = dpp_add<0x142>(x);   // row_bcast:15
    x = dpp_add<0x143>(x);   // row_bcast:31 -> lane63 = total
    return __int_as_float(__builtin_amdgcn_readlane(__float_as_int(x), 63));
}

// ---------------------------------------------------------------------------
// Prep: softmax(transition) -> ws[0..4095]   (A[i][j], row-major)
//       softmax(emission)   -> ws[4096..6143] (B[n][s], row-major)
//       softmax(init)       -> ws[6144..6207] (I[n])
// ---------------------------------------------------------------------------
__global__ __launch_bounds__(64) void hmm_prep(
    const float* __restrict__ em, const float* __restrict__ tr,
    const float* __restrict__ ini, float* __restrict__ ws)
{
    const int n = threadIdx.x;

    {
        float a[64];
        float m = -1e30f;
        #pragma unroll
        for (int j = 0; j < 64; ++j) { a[j] = tr[n * 64 + j]; m = fmaxf(m, a[j]); }
        float s = 0.f;
        #pragma unroll
        for (int j = 0; j < 64; ++j) { a[j] = __expf(a[j] - m); s += a[j]; }
        const float inv = 1.f / s;
        #pragma unroll
        for (int j = 0; j < 64; ++j) ws[n * 64 + j] = a[j] * inv;
    }
    {
        float bv[32];
        float m = -1e30f;
        #pragma unroll
        for (int j = 0; j < 32; ++j) { bv[j] = em[n * 32 + j]; m = fmaxf(m, bv[j]); }
        float s = 0.f;
        #pragma unroll
        for (int j = 0; j < 32; ++j) { bv[j] = __expf(bv[j] - m); s += bv[j]; }
        const float inv = 1.f / s;
        #pragma unroll
        for (int j = 0; j < 32; ++j) ws[4096 + n * 32 + j] = bv[j] * inv;
    }
    {
        float v = ini[n];
        float m = v;
        #pragma unroll
        for (int off = 32; off; off >>= 1) m = fmaxf(m, __shfl_xor(m, off, 64));
        const float e = __expf(v - m);
        float s = e;
        #pragma unroll
        for (int off = 32; off; off >>= 1) s += __shfl_xor(s, off, 64);
        ws[6144 + n] = e / s;
    }
}

// ---------------------------------------------------------------------------
// Emission pass: E[b][t][n] = dot(B[n,:], x[b,t,:]) stored INTO d_out's fwd
// slots (op[t*65 + n]).  The scan reads E row t at step t and overwrites row
// t-1 at step t, so the storage never collides.
// ---------------------------------------------------------------------------
__global__ __launch_bounds__(256) void hmm_emit(
    const float* __restrict__ inputs, const float* __restrict__ ws,
    float* __restrict__ out)
{
    const int b    = blockIdx.x >> 5;
    const int chk  = blockIdx.x & 31;    // 32 t-rows per block
    const int tid  = threadIdx.x;
    const int lane = tid & 63;
    const int w    = tid >> 6;

    __shared__ float xs[32 * 32];
    const float* __restrict__ xp = inputs + ((size_t)b * TT + (size_t)chk * 32) * NSYM;
    reinterpret_cast<float4*>(xs)[tid] = reinterpret_cast<const float4*>(xp)[tid];

    float Brow[32];
    {
        const float4* B4 = reinterpret_cast<const float4*>(ws + 4096 + lane * 32);
        #pragma unroll
        for (int i = 0; i < 8; ++i) {
            float4 v = B4[i];
            Brow[4*i+0] = v.x; Brow[4*i+1] = v.y;
            Brow[4*i+2] = v.z; Brow[4*i+3] = v.w;
        }
    }
    __syncthreads();

    float* __restrict__ op = out + ((size_t)b * TT + (size_t)chk * 32) * 65;
    #pragma unroll
    for (int r = 0; r < 8; ++r) {
        const int trow = w * 8 + r;
        const float4* x4 = reinterpret_cast<const float4*>(xs + trow * 32);
        float e0 = 0.f, e1 = 0.f, e2 = 0.f, e3 = 0.f;
        #pragma unroll
        for (int i = 0; i < 8; ++i) {
            float4 v = x4[i];
            e0 = fmaf(Brow[4*i+0], v.x, e0);
            e1 = fmaf(Brow[4*i+1], v.y, e1);
            e2 = fmaf(Brow[4*i+2], v.z, e2);
            e3 = fmaf(Brow[4*i+3], v.w, e3);
        }
        op[(size_t)trow * 65 + lane] = (e0 + e1) + (e2 + e3);
    }
}

// ---------------------------------------------------------------------------
// Scan: 2 waves per block (different SIMDs), one chain per wave, lane = state.
// NO LDS: the h broadcast for the matvec goes through v_readlane -> SGPRs.
//   pack (h[2i],h[2i+1]) into half2 in even lanes (1 DPP row_shl:1 + cvt_pkrtz),
//   32x v_readlane (const lane) -> SGPR, 32x v_dot2_f32_f16 against pre-packed
//   f16 A-columns, 8 accumulator chains.
// Unnormalized recurrence h_t = (E_t * sc_t) o (A^T h_{t-1}); sc_t an exact
// power of 2 from the stale exponent of h_{t-1}[0]; integer Esum compensates.
// Outputs (f_t, ll_t) are pure functions of h_t, emitted one step delayed.
// ---------------------------------------------------------------------------
__global__ __launch_bounds__(128) void hmm_scan(
    const float* __restrict__ ws, float* __restrict__ out)
{
    const int w    = threadIdx.x >> 6;
    const int lane = threadIdx.x & 63;
    const int b    = blockIdx.x * 2 + w;

#if __has_builtin(__builtin_amdgcn_fdot2)
    // packed A columns: apk[d] = (A[2d][lane], A[2d+1][lane]) as half2
    int apk[32];
    #pragma unroll
    for (int d = 0; d < 32; ++d) {
        const float a0 = ws[(2 * d)     * 64 + lane];
        const float a1 = ws[(2 * d + 1) * 64 + lane];
        apk[d] = __builtin_bit_cast(int, __builtin_amdgcn_cvt_pkrtz(a0, a1));
    }
#else
    float Acol[64];
    #pragma unroll
    for (int i = 0; i < 64; ++i) Acol[i] = ws[i * 64 + lane];
#endif
    const float Iv_l = ws[6144 + lane];

    float* __restrict__ op = out + (size_t)b * (TT * 65);

    // E ring: rows 0..7
    float eR[8];
    #pragma unroll
    for (int k = 0; k < 8; ++k) eR[k] = op[k * 65 + lane];

    float hprev = 0.f;
    int   Esum  = 0;

    auto body = [&](int t, int j, bool refill) {
        const bool is0 = (t == 0);

        // ---- scale feedback (SALU; resolves under the matvec) ----
        const unsigned bits = __builtin_amdgcn_readfirstlane(__float_as_uint(hprev));
        int ex = (int)((bits >> 23) & 255u);
        ex = ex < 1 ? 1 : (ex > 253 ? 253 : ex);
        float sc = __uint_as_float((unsigned)(254 - ex) << 23);   // 2^(127-ex)
        sc = is0 ? 1.0f : sc;
        const int EsumPrev = Esum;
        Esum += is0 ? 0 : (ex - 127);

        // ---- VALU-only reduce of h_{t-1} (feeds only delayed outputs) ----
        const float S = wave64_sum_sgpr(hprev);

        // ---- off-critical-path: pre-scale the emission ----
        const float eRs = eR[j] * sc;

        // ---- critical path: matvec via readlane broadcast ----
#if __has_builtin(__builtin_amdgcn_fdot2)
        // even lane 2i gets (h[2i], h[2i+1]): row_shl:1 brings lane l+1's h
        const int hnb = __builtin_amdgcn_update_dpp(
            0, __float_as_int(hprev), 0x101, 0xf, 0xf, true);
        const int hpki = __builtin_bit_cast(int,
            __builtin_amdgcn_cvt_pkrtz(hprev, __int_as_float(hnb)));

        float r0 = 0.f, r1 = 0.f, r2 = 0.f, r3 = 0.f;
        float r4 = 0.f, r5 = 0.f, r6 = 0.f, r7 = 0.f;
        #pragma unroll
        for (int d = 0; d < 4; ++d) {
            const int h0 = __builtin_amdgcn_readlane(hpki, 16 * d + 0);
            const int h1 = __builtin_amdgcn_readlane(hpki, 16 * d + 2);
            const int h2 = __builtin_amdgcn_readlane(hpki, 16 * d + 4);
            const int h3 = __builtin_amdgcn_readlane(hpki, 16 * d + 6);
            const int h4 = __builtin_amdgcn_readlane(hpki, 16 * d + 8);
            const int h5 = __builtin_amdgcn_readlane(hpki, 16 * d + 10);
            const int h6 = __builtin_amdgcn_readlane(hpki, 16 * d + 12);
            const int h7 = __builtin_amdgcn_readlane(hpki, 16 * d + 14);
            r0 = __builtin_amdgcn_fdot2(__builtin_bit_cast(half2v, h0),
                                        __builtin_bit_cast(half2v, apk[8*d+0]), r0, false);
            r1 = __builtin_amdgcn_fdot2(__builtin_bit_cast(half2v, h1),
                                        __builtin_bit_cast(half2v, apk[8*d+1]), r1, false);
            r2 = __builtin_amdgcn_fdot2(__builtin_bit_cast(half2v, h2),
                                        __builtin_bit_cast(half2v, apk[8*d+2]), r2, false);
            r3 = __builtin_amdgcn_fdot2(__builtin_bit_cast(half2v, h3),
                                        __builtin_bit_cast(half2v, apk[8*d+3]), r3, false);
            r4 = __builtin_amdgcn_fdot2(__builtin_bit_cast(half2v, h4),
                                        __builtin_bit_cast(half2v, apk[8*d+4]), r4, false);
            r5 = __builtin_amdgcn_fdot2(__builtin_bit_cast(half2v, h5),
                                        __builtin_bit_cast(half2v, apk[8*d+5]), r5, false);
            r6 = __builtin_amdgcn_fdot2(__builtin_bit_cast(half2v, h6),
                                        __builtin_bit_cast(half2v, apk[8*d+6]), r6, false);
            r7 = __builtin_amdgcn_fdot2(__builtin_bit_cast(half2v, h7),
                                        __builtin_bit_cast(half2v, apk[8*d+7]), r7, false);
        }
#else
        float r0 = 0.f, r1 = 0.f, r2 = 0.f, r3 = 0.f;
        float r4 = 0.f, r5 = 0.f, r6 = 0.f, r7 = 0.f;
        const int hbits = __float_as_int(hprev);
        #pragma unroll
        for (int d = 0; d < 8; ++d) {
            r0 = fmaf(__int_as_float(__builtin_amdgcn_readlane(hbits, 8*d+0)), Acol[8*d+0], r0);
            r1 = fmaf(__int_as_float(__builtin_amdgcn_readlane(hbits, 8*d+1)), Acol[8*d+1], r1);
            r2 = fmaf(__int_as_float(__builtin_amdgcn_readlane(hbits, 8*d+2)), Acol[8*d+2], r2);
            r3 = fmaf(__int_as_float(__builtin_amdgcn_readlane(hbits, 8*d+3)), Acol[8*d+3], r3);
            r4 = fmaf(__int_as_float(__builtin_amdgcn_readlane(hbits, 8*d+4)), Acol[8*d+4], r4);
            r5 = fmaf(__int_as_float(__builtin_amdgcn_readlane(hbits, 8*d+5)), Acol[8*d+5], r5);
            r6 = fmaf(__int_as_float(__builtin_amdgcn_readlane(hbits, 8*d+6)), Acol[8*d+6], r6);
            r7 = fmaf(__int_as_float(__builtin_amdgcn_readlane(hbits, 8*d+7)), Acol[8*d+7], r7);
        }
#endif
        float mv = ((r0 + r1) + (r2 + r3)) + ((r4 + r5) + (r6 + r7));
        mv = is0 ? Iv_l : mv;

        const float h = eRs * mv;    // sc already folded into eRs

        // refill E ring with row t+8 (main loop only; t+8 <= 1023 there)
        if (refill) eR[j] = op[(t + 8) * 65 + lane];

        // ---- delayed outputs for step t-1 (t=0 writes junk to row 0,
        //      overwritten at t=1; row 0's E was consumed already) ----
        const int tp = is0 ? 0 : (t - 1);
        const float r = __builtin_amdgcn_rcpf(S);
        op[tp * 65 + lane] = hprev * r;
        if (lane == 0) op[tp * 65 + 64] = __logf(S) + (float)EsumPrev * LN2F;

        hprev = h;
    };

    for (int Q = 0; Q < 127; ++Q) {
        #pragma unroll
        for (int j = 0; j < 8; ++j) body(Q * 8 + j, j, true);
    }
    #pragma unroll
    for (int j = 0; j < 8; ++j) body(1016 + j, j, false);   // tail: no refill

    // Epilogue: outputs for t = 1023
    {
        const float S = wave64_sum_sgpr(hprev);
        const float r = __builtin_amdgcn_rcpf(S);
        op[1023 * 65 + lane] = hprev * r;
        if (lane == 0) op[1023 * 65 + 64] = __logf(S) + (float)Esum * LN2F;
    }
}

// ---------------------------------------------------------------------------
extern "C" void kernel_launch(void* const* d_in, const int* in_sizes, int n_in,
                              void* d_out, int out_size, void* d_ws, size_t ws_size,
                              hipStream_t stream) {
    const float* inputs = (const float*)d_in[0];  // [512,1024,32]
    const float* em     = (const float*)d_in[1];  // [64,32]
    const float* tr     = (const float*)d_in[2];  // [64,64]
    const float* ini    = (const float*)d_in[3];  // [64]
    float* out = (float*)d_out;                   // [512,1024,65]
    float* ws  = (float*)d_ws;                    // 6208 floats used

    hmm_prep<<<1, 64, 0, stream>>>(em, tr, ini, ws);
    hmm_emit<<<BATCH * (TT / 32), 256, 0, stream>>>(inputs, ws, out);
    hmm_scan<<<BATCH / 2, 128, 0, stream>>>(ws, out);
}

// Round 7
// 339.819 us; speedup vs baseline: 2.3861x; 1.0132x over previous
//
#include <hip/hip_runtime.h>

#define BATCH 512
#define TT    1024
#define NST   64
#define NSYM  32
#define LN2F  0.69314718055994530942f

typedef _Float16 half2v __attribute__((ext_vector_type(2)));

// ---------------------------------------------------------------------------
// Wave64 sum reduction on the VALU only (DPP row ops, rocPRIM pattern).
// bound_ctrl=1: out-of-range source lanes contribute 0. Total lands in lane 63.
// ---------------------------------------------------------------------------
template <int CTRL>
__device__ __forceinline__ float dpp_add(float x) {
    int y = __builtin_amdgcn_update_dpp(0, __float_as_int(x), CTRL, 0xf, 0xf, true);
    return x + __int_as_float(y);
}
__device__ __forceinline__ float wave64_sum_sgpr(float x) {
    x = dpp_add<0x111>(x);   // row_shr:1
    x = dpp_add<0x112>(x);   // row_shr:2
    x = dpp_add<0x114>(x);   // row_shr:4
    x = dpp_add<0x118>(x);   // row_shr:8
    x = dpp_add<0x142>(x);   // row_bcast:15
    x = dpp_add<0x143>(x);   // row_bcast:31 -> lane63 = total
    return __int_as_float(__builtin_amdgcn_readlane(__float_as_int(x), 63));
}

// ---------------------------------------------------------------------------
// Prep: softmax(transition) -> ws[0..4095]   (A[i][j], row-major)
//       softmax(emission)   -> ws[4096..6143] (B[n][s], row-major)
//       softmax(init)       -> ws[6144..6207] (I[n])
// ---------------------------------------------------------------------------
__global__ __launch_bounds__(64) void hmm_prep(
    const float* __restrict__ em, const float* __restrict__ tr,
    const float* __restrict__ ini, float* __restrict__ ws)
{
    const int n = threadIdx.x;

    {
        float a[64];
        float m = -1e30f;
        #pragma unroll
        for (int j = 0; j < 64; ++j) { a[j] = tr[n * 64 + j]; m = fmaxf(m, a[j]); }
        float s = 0.f;
        #pragma unroll
        for (int j = 0; j < 64; ++j) { a[j] = __expf(a[j] - m); s += a[j]; }
        const float inv = 1.f / s;
        #pragma unroll
        for (int j = 0; j < 64; ++j) ws[n * 64 + j] = a[j] * inv;
    }
    {
        float bv[32];
        float m = -1e30f;
        #pragma unroll
        for (int j = 0; j < 32; ++j) { bv[j] = em[n * 32 + j]; m = fmaxf(m, bv[j]); }
        float s = 0.f;
        #pragma unroll
        for (int j = 0; j < 32; ++j) { bv[j] = __expf(bv[j] - m); s += bv[j]; }
        const float inv = 1.f / s;
        #pragma unroll
        for (int j = 0; j < 32; ++j) ws[4096 + n * 32 + j] = bv[j] * inv;
    }
    {
        float v = ini[n];
        float m = v;
        #pragma unroll
        for (int off = 32; off; off >>= 1) m = fmaxf(m, __shfl_xor(m, off, 64));
        const float e = __expf(v - m);
        float s = e;
        #pragma unroll
        for (int off = 32; off; off >>= 1) s += __shfl_xor(s, off, 64);
        ws[6144 + n] = e / s;
    }
}

// ---------------------------------------------------------------------------
// Emission pass: E[b][t][n] = dot(B[n,:], x[b,t,:]) stored INTO d_out's fwd
// slots (op[t*65 + n]).  The scan reads E row t at step t and overwrites row
// t-1 at step t, so the storage never collides.
// ---------------------------------------------------------------------------
__global__ __launch_bounds__(256) void hmm_emit(
    const float* __restrict__ inputs, const float* __restrict__ ws,
    float* __restrict__ out)
{
    const int b    = blockIdx.x >> 5;
    const int chk  = blockIdx.x & 31;    // 32 t-rows per block
    const int tid  = threadIdx.x;
    const int lane = tid & 63;
    const int w    = tid >> 6;

    __shared__ float xs[32 * 32];
    const float* __restrict__ xp = inputs + ((size_t)b * TT + (size_t)chk * 32) * NSYM;
    reinterpret_cast<float4*>(xs)[tid] = reinterpret_cast<const float4*>(xp)[tid];

    float Brow[32];
    {
        const float4* B4 = reinterpret_cast<const float4*>(ws + 4096 + lane * 32);
        #pragma unroll
        for (int i = 0; i < 8; ++i) {
            float4 v = B4[i];
            Brow[4*i+0] = v.x; Brow[4*i+1] = v.y;
            Brow[4*i+2] = v.z; Brow[4*i+3] = v.w;
        }
    }
    __syncthreads();

    float* __restrict__ op = out + ((size_t)b * TT + (size_t)chk * 32) * 65;
    #pragma unroll
    for (int r = 0; r < 8; ++r) {
        const int trow = w * 8 + r;
        const float4* x4 = reinterpret_cast<const float4*>(xs + trow * 32);
        float e0 = 0.f, e1 = 0.f, e2 = 0.f, e3 = 0.f;
        #pragma unroll
        for (int i = 0; i < 8; ++i) {
            float4 v = x4[i];
            e0 = fmaf(Brow[4*i+0], v.x, e0);
            e1 = fmaf(Brow[4*i+1], v.y, e1);
            e2 = fmaf(Brow[4*i+2], v.z, e2);
            e3 = fmaf(Brow[4*i+3], v.w, e3);
        }
        op[(size_t)trow * 65 + lane] = (e0 + e1) + (e2 + e3);
    }
}

// ---------------------------------------------------------------------------
// Scan: 2 waves per block (different SIMDs), one chain per wave, lane = state.
// NO LDS: matvec broadcast via v_readlane -> SGPR, 32x v_dot2_f32_f16 against
// REGISTER-PINNED packed f16 A-columns (asm pin prevents the compiler from
// demoting apk[] -- R6 shipped with VGPR_Count=32, i.e. apk rematerialized
// in-loop).  t=0 peeled (no matvec, no selects in the hot body).
// Unnormalized recurrence h_t = (E_t * sc_t) o (A^T h_{t-1}); sc_t an exact
// power of 2 from the stale exponent of h_{t-1}[0]; integer Esum compensates.
// Outputs (f_t, ll_t) are pure functions of h_t, emitted one step delayed.
// ---------------------------------------------------------------------------
__global__ __launch_bounds__(128, 1) void hmm_scan(
    const float* __restrict__ ws, float* __restrict__ out)
{
    const int w    = threadIdx.x >> 6;
    const int lane = threadIdx.x & 63;
    const int b    = blockIdx.x * 2 + w;

#if __has_builtin(__builtin_amdgcn_fdot2)
    // packed A columns: apk[d] = (A[2d][lane], A[2d+1][lane]) as half2
    int apk[32];
    #pragma unroll
    for (int d = 0; d < 32; ++d) {
        const float a0 = ws[(2 * d)     * 64 + lane];
        const float a1 = ws[(2 * d + 1) * 64 + lane];
        apk[d] = __builtin_bit_cast(int, __builtin_amdgcn_cvt_pkrtz(a0, a1));
    }
    // PIN: make each element an opaque VGPR value -- no remat, no sinking.
    #pragma unroll
    for (int d = 0; d < 32; ++d) asm volatile("" : "+v"(apk[d]));
#else
    float Acol[64];
    #pragma unroll
    for (int i = 0; i < 64; ++i) Acol[i] = ws[i * 64 + lane];
    #pragma unroll
    for (int i = 0; i < 64; ++i) asm volatile("" : "+v"(Acol[i]));
#endif
    const float Iv_l = ws[6144 + lane];

    float* __restrict__ op = out + (size_t)b * (TT * 65);

    // E ring: rows 0..7
    float eR[8];
    #pragma unroll
    for (int k = 0; k < 8; ++k) eR[k] = op[k * 65 + lane];

    // ---- t = 0 peeled: h0 = E0 o I (no matvec, sc = 1) ----
    float hprev = eR[0] * Iv_l;
    eR[0] = op[8 * 65 + lane];      // refill row 8 (consumed at t=8)
    int Esum = 0;

    // body for t >= 1
    auto body = [&](int t, int j, bool refill) {
        // ---- scale feedback (SALU; resolves under the matvec) ----
        const unsigned bits = __builtin_amdgcn_readfirstlane(__float_as_uint(hprev));
        int ex = (int)((bits >> 23) & 255u);
        ex = ex < 1 ? 1 : (ex > 253 ? 253 : ex);
        const float sc = __uint_as_float((unsigned)(254 - ex) << 23);   // 2^(127-ex)
        const int EsumPrev = Esum;
        Esum += ex - 127;

        // ---- VALU-only reduce of h_{t-1} (feeds only delayed outputs) ----
        const float S = wave64_sum_sgpr(hprev);

        // ---- off-critical-path: pre-scale the emission ----
        const float eRs = eR[j] * sc;

        // ---- critical path: matvec via readlane broadcast ----
#if __has_builtin(__builtin_amdgcn_fdot2)
        // even lane 2i gets (h[2i], h[2i+1]): row_shl:1 brings lane l+1's h
        const int hnb = __builtin_amdgcn_update_dpp(
            0, __float_as_int(hprev), 0x101, 0xf, 0xf, true);
        const int hpki = __builtin_bit_cast(int,
            __builtin_amdgcn_cvt_pkrtz(hprev, __int_as_float(hnb)));

        float r0 = 0.f, r1 = 0.f, r2 = 0.f, r3 = 0.f;
        float r4 = 0.f, r5 = 0.f, r6 = 0.f, r7 = 0.f;
        #pragma unroll
        for (int d = 0; d < 4; ++d) {
            const int h0 = __builtin_amdgcn_readlane(hpki, 16 * d + 0);
            const int h1 = __builtin_amdgcn_readlane(hpki, 16 * d + 2);
            const int h2 = __builtin_amdgcn_readlane(hpki, 16 * d + 4);
            const int h3 = __builtin_amdgcn_readlane(hpki, 16 * d + 6);
            const int h4 = __builtin_amdgcn_readlane(hpki, 16 * d + 8);
            const int h5 = __builtin_amdgcn_readlane(hpki, 16 * d + 10);
            const int h6 = __builtin_amdgcn_readlane(hpki, 16 * d + 12);
            const int h7 = __builtin_amdgcn_readlane(hpki, 16 * d + 14);
            r0 = __builtin_amdgcn_fdot2(__builtin_bit_cast(half2v, h0),
                                        __builtin_bit_cast(half2v, apk[8*d+0]), r0, false);
            r1 = __builtin_amdgcn_fdot2(__builtin_bit_cast(half2v, h1),
                                        __builtin_bit_cast(half2v, apk[8*d+1]), r1, false);
            r2 = __builtin_amdgcn_fdot2(__builtin_bit_cast(half2v, h2),
                                        __builtin_bit_cast(half2v, apk[8*d+2]), r2, false);
            r3 = __builtin_amdgcn_fdot2(__builtin_bit_cast(half2v, h3),
                                        __builtin_bit_cast(half2v, apk[8*d+3]), r3, false);
            r4 = __builtin_amdgcn_fdot2(__builtin_bit_cast(half2v, h4),
                                        __builtin_bit_cast(half2v, apk[8*d+4]), r4, false);
            r5 = __builtin_amdgcn_fdot2(__builtin_bit_cast(half2v, h5),
                                        __builtin_bit_cast(half2v, apk[8*d+5]), r5, false);
            r6 = __builtin_amdgcn_fdot2(__builtin_bit_cast(half2v, h6),
                                        __builtin_bit_cast(half2v, apk[8*d+6]), r6, false);
            r7 = __builtin_amdgcn_fdot2(__builtin_bit_cast(half2v, h7),
                                        __builtin_bit_cast(half2v, apk[8*d+7]), r7, false);
        }
#else
        float r0 = 0.f, r1 = 0.f, r2 = 0.f, r3 = 0.f;
        float r4 = 0.f, r5 = 0.f, r6 = 0.f, r7 = 0.f;
        const int hbits = __float_as_int(hprev);
        #pragma unroll
        for (int d = 0; d < 8; ++d) {
            r0 = fmaf(__int_as_float(__builtin_amdgcn_readlane(hbits, 8*d+0)), Acol[8*d+0], r0);
            r1 = fmaf(__int_as_float(__builtin_amdgcn_readlane(hbits, 8*d+1)), Acol[8*d+1], r1);
            r2 = fmaf(__int_as_float(__builtin_amdgcn_readlane(hbits, 8*d+2)), Acol[8*d+2], r2);
            r3 = fmaf(__int_as_float(__builtin_amdgcn_readlane(hbits, 8*d+3)), Acol[8*d+3], r3);
            r4 = fmaf(__int_as_float(__builtin_amdgcn_readlane(hbits, 8*d+4)), Acol[8*d+4], r4);
            r5 = fmaf(__int_as_float(__builtin_amdgcn_readlane(hbits, 8*d+5)), Acol[8*d+5], r5);
            r6 = fmaf(__int_as_float(__builtin_amdgcn_readlane(hbits, 8*d+6)), Acol[8*d+6], r6);
            r7 = fmaf(__int_as_float(__builtin_amdgcn_readlane(hbits, 8*d+7)), Acol[8*d+7], r7);
        }
#endif
        const float mv = ((r0 + r1) + (r2 + r3)) + ((r4 + r5) + (r6 + r7));
        const float h = eRs * mv;

        // refill E ring with row t+8 (only while t+8 <= 1023)
        if (refill) eR[j] = op[(t + 8) * 65 + lane];

        // ---- delayed outputs for step t-1 ----
        const float r = __builtin_amdgcn_rcpf(S);
        op[(t - 1) * 65 + lane] = hprev * r;
        if (lane == 0) op[(t - 1) * 65 + 64] = __logf(S) + (float)EsumPrev * LN2F;

        hprev = h;
    };

    // t = 1..7  (j = t; refill rows 9..15)
    #pragma unroll
    for (int j = 1; j < 8; ++j) body(j, j, true);
    // t = 8..1015 in groups of 8 (refill rows 16..1023)
    for (int Q = 1; Q < 127; ++Q) {
        #pragma unroll
        for (int j = 0; j < 8; ++j) body(Q * 8 + j, j, true);
    }
    // t = 1016..1023: no refill
    #pragma unroll
    for (int j = 0; j < 8; ++j) body(1016 + j, j, false);

    // Epilogue: outputs for t = 1023
    {
        const float S = wave64_sum_sgpr(hprev);
        const float r = __builtin_amdgcn_rcpf(S);
        op[1023 * 65 + lane] = hprev * r;
        if (lane == 0) op[1023 * 65 + 64] = __logf(S) + (float)Esum * LN2F;
    }
}

// ---------------------------------------------------------------------------
extern "C" void kernel_launch(void* const* d_in, const int* in_sizes, int n_in,
                              void* d_out, int out_size, void* d_ws, size_t ws_size,
                              hipStream_t stream) {
    const float* inputs = (const float*)d_in[0];  // [512,1024,32]
    const float* em     = (const float*)d_in[1];  // [64,32]
    const float* tr     = (const float*)d_in[2];  // [64,64]
    const float* ini    = (const float*)d_in[3];  // [64]
    float* out = (float*)d_out;                   // [512,1024,65]
    float* ws  = (float*)d_ws;                    // 6208 floats used

    hmm_prep<<<1, 64, 0, stream>>>(em, tr, ini, ws);
    hmm_emit<<<BATCH * (TT / 32), 256, 0, stream>>>(inputs, ws, out);
    hmm_scan<<<BATCH / 2, 128, 0, stream>>>(ws, out);
}